// Round 4
// baseline (215.735 us; speedup 1.0000x reference)
//
#include <hip/hip_runtime.h>

typedef float f32x4 __attribute__((ext_vector_type(4)));

#define B_ 32
#define N_ 1024
#define D_ 512
#define K_ 64
#define KG_ 80

// ---------------------------------------------------------------------------
// K0: fold BN into affine sc/sh; zero the atomically-accumulated buffers.
// ---------------------------------------------------------------------------
__global__ void k_prep(const float* __restrict__ bn_w, const float* __restrict__ bn_b,
                       const float* __restrict__ bn_m, const float* __restrict__ bn_v,
                       float* __restrict__ bn_sc, float* __restrict__ bn_sh,
                       float* __restrict__ asum, float* __restrict__ ssq) {
  int t = blockIdx.x * 256 + threadIdx.x;
  if (t < KG_) {
    float sc = bn_w[t] * rsqrtf(bn_v[t] + 1e-5f);
    bn_sc[t] = sc;
    bn_sh[t] = bn_b[t] - bn_m[t] * sc;
  }
  if (t < B_ * K_) asum[t] = 0.0f;
  if (t < B_) ssq[t] = 0.0f;
}

// ---------------------------------------------------------------------------
// K1: assignment = softmax(BN(x @ clusters))[:, :64]  +  a_sum[b,k]
// 1024 blocks x 256 thr. M-tile 32 rows, N=80, K chunks of 64.
// LDS: cluster chunk [64][80] (broadcast reads, conflict-free) + x [32][66].
// Thread tile 2 rows x 5 cols -> 20 FMA per 2-d step vs ~7 LDS instrs.
// 32.5 KB LDS -> 4 blocks/CU (50% occupancy).
// ---------------------------------------------------------------------------
__global__ __launch_bounds__(256, 4) void k_assign(
    const float* __restrict__ x, const float* __restrict__ clusters,
    const float* __restrict__ bn_sc, const float* __restrict__ bn_sh,
    float* __restrict__ a_ws, float* __restrict__ asum_g) {
  __shared__ float xs[32 * 66];     // [row][66] one 64-d chunk (pad 2)
  __shared__ float cT[64 * 80];     // [d][80] cluster chunk
  __shared__ float mxr[32][17];
  __shared__ float smr[32][17];

  int t  = threadIdx.x;
  int rg = t & 15;                  // rows 2rg, 2rg+1
  int cg = t >> 4;                  // cols 5cg .. 5cg+4
  int r0 = blockIdx.x * 32;
  int b  = blockIdx.x >> 5;         // 32 blocks per batch

  // per-thread BN coefficients (read once)
  float sc5[5], sh5[5];
#pragma unroll
  for (int j = 0; j < 5; j++) { sc5[j] = bn_sc[5 * cg + j]; sh5[j] = bn_sh[5 * cg + j]; }

  float acc[2][5] = {{0.0f}};
  const float* xgb = x + (size_t)r0 * 512;
  int srow = t >> 4, scb = (t & 15) * 4;

  for (int c0 = 0; c0 < 512; c0 += 64) {
    // issue global loads into regs first (latency overlaps prev compute)
    f32x4 xv0 = *(const f32x4*)&xgb[(size_t)srow * 512 + c0 + scb];
    f32x4 xv1 = *(const f32x4*)&xgb[(size_t)(srow + 16) * 512 + c0 + scb];
    const f32x4* cg4 = (const f32x4*)(clusters + (size_t)c0 * 80);
    f32x4 cv[5];
#pragma unroll
    for (int j = 0; j < 5; j++) cv[j] = cg4[t + 256 * j];

    __syncthreads();                // previous chunk's compute done
    *(f32x4*)&xs[srow * 66 + scb] = xv0;
    *(f32x4*)&xs[(srow + 16) * 66 + scb] = xv1;
    f32x4* ct4 = (f32x4*)cT;
#pragma unroll
    for (int j = 0; j < 5; j++) ct4[t + 256 * j] = cv[j];
    __syncthreads();

    const float* xr0 = &xs[(2 * rg) * 66];
    const float* xr1 = &xs[(2 * rg + 1) * 66];
    const float* cc  = &cT[5 * cg];
#pragma unroll 4
    for (int d = 0; d < 64; d += 2) {
      float x00 = xr0[d], x01 = xr0[d + 1];
      float x10 = xr1[d], x11 = xr1[d + 1];
      const float* c0p = &cc[d * 80];
      const float* c1p = &cc[d * 80 + 80];
#pragma unroll
      for (int j = 0; j < 5; j++) {
        float cj0 = c0p[j], cj1 = c1p[j];
        acc[0][j] = fmaf(x00, cj0, acc[0][j]);
        acc[0][j] = fmaf(x01, cj1, acc[0][j]);
        acc[1][j] = fmaf(x10, cj0, acc[1][j]);
        acc[1][j] = fmaf(x11, cj1, acc[1][j]);
      }
    }
  }

  // BN affine + per-thread softmax partials (5 cols x 2 rows)
  float lj[2][5], mx[2], sm[2];
#pragma unroll
  for (int i = 0; i < 2; i++) {
    mx[i] = -3.0e38f;
#pragma unroll
    for (int j = 0; j < 5; j++) {
      float l = fmaf(acc[i][j], sc5[j], sh5[j]);
      lj[i][j] = l;
      mx[i] = fmaxf(mx[i], l);
    }
    sm[i] = 0.0f;
#pragma unroll
    for (int j = 0; j < 5; j++) { lj[i][j] = __expf(lj[i][j] - mx[i]); sm[i] += lj[i][j]; }
    mxr[2 * rg + i][cg] = mx[i];
    smr[2 * rg + i][cg] = sm[i];
  }
  __syncthreads();

  if (t < 32) {                     // per-row reduce over 16 col-groups
    float M = -3.0e38f;
#pragma unroll
    for (int g = 0; g < 16; g++) M = fmaxf(M, mxr[t][g]);
    float S = 0.0f;
#pragma unroll
    for (int g = 0; g < 16; g++) S += smr[t][g] * __expf(mxr[t][g] - M);
    mxr[t][16] = M;
    smr[t][16] = S;
  }
  __syncthreads();

  float p[2][5];
#pragma unroll
  for (int i = 0; i < 2; i++) {
    int row = 2 * rg + i;
    float M = mxr[row][16], S = smr[row][16];
    float f = __expf(mx[i] - M) / S;
    float* arow = a_ws + (size_t)(r0 + row) * 64 + 5 * cg;
#pragma unroll
    for (int j = 0; j < 5; j++) {
      p[i][j] = lj[i][j] * f;
      if (5 * cg + j < 64) arow[j] = p[i][j];
    }
  }
  // a_sum: reduce the block's 32 rows per column (rg bits live in lane bits 0..3)
#pragma unroll
  for (int j = 0; j < 5; j++) {
    float s = p[0][j] + p[1][j];
    s += __shfl_xor(s, 1); s += __shfl_xor(s, 2);
    s += __shfl_xor(s, 4); s += __shfl_xor(s, 8);
    int col = 5 * cg + j;
    if (rg == 0 && col < 64) atomicAdd(&asum_g[b * 64 + col], s);
  }
}

// ---------------------------------------------------------------------------
// K2: vlad[b,d,k] = sum_n a[b,n,k]*x[b,n,d] - a_sum[b,k]*c2[d,k]
// 512 blocks (32 b x 16 d-tiles of 32) -> 2 blocks/CU. bid = b + 32*dt keeps
// a batch's tiles on one XCD (bid%8 = b%8) so a_ws[b]/x[b] are L2-shared.
// Thread tile 2d x 4k; global loads issued before the barrier (latency hide).
// ---------------------------------------------------------------------------
__global__ __launch_bounds__(256, 2) void k_vlad(
    const float* __restrict__ x, const float* __restrict__ a_ws,
    const float* __restrict__ asum_g, const float* __restrict__ c2,
    float* __restrict__ vlad, float* __restrict__ ssq) {
  __shared__ float xs[64 * 36];     // [n][36] d-slice
  __shared__ float as[64 * 68];     // [n][68]
  __shared__ float wsum[4];

  int t  = threadIdx.x;
  int b  = blockIdx.x & 31;
  int d0 = (blockIdx.x >> 5) * 32;
  int kg = t & 15, dg = t >> 4;     // k = 4kg..+3, d = d0+2dg..+1
  float acc[2][4] = {{0.0f}};

  const float* xb = x + (size_t)b * 1024 * 512 + d0;
  const float* ab = a_ws + (size_t)b * 1024 * 64;
  int xn = t >> 3, xc = (t & 7) * 4;
  int an = t >> 4, ac = (t & 15) * 4;

  for (int n0 = 0; n0 < 1024; n0 += 64) {
    f32x4 xv0 = *(const f32x4*)&xb[(size_t)(n0 + xn) * 512 + xc];
    f32x4 xv1 = *(const f32x4*)&xb[(size_t)(n0 + xn + 32) * 512 + xc];
    f32x4 av0 = *(const f32x4*)&ab[(size_t)(n0 + an) * 64 + ac];
    f32x4 av1 = *(const f32x4*)&ab[(size_t)(n0 + an + 16) * 64 + ac];
    f32x4 av2 = *(const f32x4*)&ab[(size_t)(n0 + an + 32) * 64 + ac];
    f32x4 av3 = *(const f32x4*)&ab[(size_t)(n0 + an + 48) * 64 + ac];

    __syncthreads();                // previous chunk's compute done
    *(f32x4*)&xs[xn * 36 + xc] = xv0;
    *(f32x4*)&xs[(xn + 32) * 36 + xc] = xv1;
    *(f32x4*)&as[an * 68 + ac] = av0;
    *(f32x4*)&as[(an + 16) * 68 + ac] = av1;
    *(f32x4*)&as[(an + 32) * 68 + ac] = av2;
    *(f32x4*)&as[(an + 48) * 68 + ac] = av3;
    __syncthreads();

#pragma unroll 8
    for (int n = 0; n < 64; n++) {
      float x0 = xs[n * 36 + 2 * dg];
      float x1 = xs[n * 36 + 2 * dg + 1];
      f32x4 ar = *(const f32x4*)&as[n * 68 + 4 * kg];
#pragma unroll
      for (int j = 0; j < 4; j++) {
        acc[0][j] = fmaf(x0, ar[j], acc[0][j]);
        acc[1][j] = fmaf(x1, ar[j], acc[1][j]);
      }
    }
  }

  float asv[4];
#pragma unroll
  for (int j = 0; j < 4; j++) asv[j] = asum_g[b * 64 + 4 * kg + j];
  float lssq = 0.0f;
#pragma unroll
  for (int i = 0; i < 2; i++) {
    int d = d0 + 2 * dg + i;
    f32x4 cv = *(const f32x4*)&c2[(size_t)d * 64 + 4 * kg];
    f32x4 o;
#pragma unroll
    for (int j = 0; j < 4; j++) {
      float val = acc[i][j] - asv[j] * cv[j];
      o[j] = val;
      lssq += val * val;
    }
    *(f32x4*)&vlad[((size_t)b * 512 + d) * 64 + 4 * kg] = o;
  }
  lssq += __shfl_xor(lssq, 1);  lssq += __shfl_xor(lssq, 2);
  lssq += __shfl_xor(lssq, 4);  lssq += __shfl_xor(lssq, 8);
  lssq += __shfl_xor(lssq, 16); lssq += __shfl_xor(lssq, 32);
  if ((t & 63) == 0) wsum[t >> 6] = lssq;
  __syncthreads();
  if (t == 0) atomicAdd(&ssq[b], wsum[0] + wsum[1] + wsum[2] + wsum[3]);
}

// ---------------------------------------------------------------------------
// K3: fold both L2 normalizations into one per-batch scale.
// ---------------------------------------------------------------------------
__global__ void k_scale(const float* __restrict__ ssq, float* __restrict__ scale) {
  int t = threadIdx.x;
  if (t < B_) {
    float S = ssq[t];
    float n1 = sqrtf(S + 1e-12f);
    float n2 = sqrtf(S / (S + 1e-12f) + 1e-12f);
    scale[t] = 1.0f / (n1 * n2);
  }
}

// ---------------------------------------------------------------------------
// K4: out = fp32(vlad * scale[b])
// ---------------------------------------------------------------------------
__global__ __launch_bounds__(256) void k_out(const float* __restrict__ vlad,
                                             const float* __restrict__ scale,
                                             float* __restrict__ out) {
  int idx = blockIdx.x * 256 + threadIdx.x;   // 4 elems per thread
  float s = scale[idx >> 13];                 // 32768 elems per batch
  f32x4 v = *(const f32x4*)&vlad[(size_t)idx * 4];
  f32x4 o;
#pragma unroll
  for (int j = 0; j < 4; j++) o[j] = v[j] * s;
  *(f32x4*)&out[(size_t)idx * 4] = o;
}

extern "C" void kernel_launch(void* const* d_in, const int* in_sizes, int n_in,
                              void* d_out, int out_size, void* d_ws, size_t ws_size,
                              hipStream_t stream) {
  const float* x        = (const float*)d_in[0];
  const float* clusters = (const float*)d_in[1];
  const float* clusters2= (const float*)d_in[2];
  const float* bn_w     = (const float*)d_in[3];
  const float* bn_b     = (const float*)d_in[4];
  const float* bn_m     = (const float*)d_in[5];
  const float* bn_v     = (const float*)d_in[6];
  float* out = (float*)d_out;

  char* ws = (char*)d_ws;
  float* a_ws  = (float*)ws;                          // 32768*64 f32 = 8 MB
  float* vlad  = (float*)(ws + (size_t)8 * 1048576);  // 32*512*64 f32 = 4 MB
  float* bn_sc = (float*)(ws + (size_t)12 * 1048576); // 80 f32
  float* bn_sh = bn_sc + KG_;
  float* asum  = bn_sh + KG_;                         // 32*64 f32
  float* ssq   = asum + B_ * K_;                      // 32 f32
  float* scale = ssq + B_;                            // 32 f32

  k_prep<<<8, 256, 0, stream>>>(bn_w, bn_b, bn_m, bn_v,
                                bn_sc, bn_sh, asum, ssq);
  k_assign<<<1024, 256, 0, stream>>>(x, clusters, bn_sc, bn_sh, a_ws, asum);
  k_vlad<<<512, 256, 0, stream>>>(x, a_ws, asum, clusters2, vlad, ssq);
  k_scale<<<1, 64, 0, stream>>>(ssq, scale);
  k_out<<<1024, 256, 0, stream>>>(vlad, scale, out);
}

// Round 5
// 155.489 us; speedup vs baseline: 1.3875x; 1.3875x over previous
//
#include <hip/hip_runtime.h>

typedef unsigned short u16;
typedef float f32x4 __attribute__((ext_vector_type(4)));
typedef short short8 __attribute__((ext_vector_type(8)));

#define B_ 32
#define N_ 1024
#define D_ 512
#define K_ 64
#define KG_ 80
#define MT_ 32768          // total rows B*N

__device__ __forceinline__ u16 f2bf(float f) {
  union { float f; unsigned u; } x; x.f = f;
  unsigned u = x.u;
  u += 0x7FFFu + ((u >> 16) & 1u);          // RNE, finite data
  return (u16)(u >> 16);
}
__device__ __forceinline__ void split2(float v, u16& h, u16& l) {
  union { float f; unsigned u; } x; x.f = v;
  unsigned hu = x.u & 0xFFFF0000u;          // truncate -> hi
  h = (u16)(hu >> 16);
  union { unsigned u; float f; } hf; hf.u = hu;
  l = f2bf(v - hf.f);                       // exact remainder, rne -> lo
}

// ---------------------------------------------------------------------------
// K0: BN fold; zero accumulators; pack clusters into MFMA B-fragments
// (hi/lo split).  cpk layout: [kk=16][h=2][cf=5][lane=64][j=8] u16
//   element = clusters[d=kk*32+(lane>>4)*8+j][col=cf*16+(lane&15)]
// ---------------------------------------------------------------------------
__global__ void k_prep(const float* __restrict__ clusters,
                       const float* __restrict__ bn_w, const float* __restrict__ bn_b,
                       const float* __restrict__ bn_m, const float* __restrict__ bn_v,
                       u16* __restrict__ cpk, float* __restrict__ bn_sc,
                       float* __restrict__ bn_sh,
                       float* __restrict__ asum, float* __restrict__ ssq) {
  int t = blockIdx.x * 256 + threadIdx.x;
  if (t < KG_) {
    float sc = bn_w[t] * rsqrtf(bn_v[t] + 1e-5f);
    bn_sc[t] = sc;
    bn_sh[t] = bn_b[t] - bn_m[t] * sc;
  }
  if (t < B_ * K_) asum[t] = 0.0f;
  if (t < B_) ssq[t] = 0.0f;
  if (t < 5120) {                            // 16 kk * 5 cf * 64 lanes
    int kk = t >> 8, cf = (t >> 6) & 3;      // careful: 5 cf doesn't split pow2
    // recompute properly: t = (kk*5 + cf)*64 + lane
    int grp = t >> 6;                        // 0..79 = kk*5+cf
    kk = grp / 5; cf = grp % 5;
    int lane = t & 63;
    int col = cf * 16 + (lane & 15);
#pragma unroll
    for (int j = 0; j < 8; j++) {
      int d = kk * 32 + ((lane >> 4) << 3) + j;
      float v = clusters[(size_t)d * 80 + col];
      u16 h, l; split2(v, h, l);
      cpk[(size_t)kk * 5120 + ((0 * 5 + cf) * 64 + lane) * 8 + j] = h;
      cpk[(size_t)kk * 5120 + ((1 * 5 + cf) * 64 + lane) * 8 + j] = l;
    }
  }
}

// ---------------------------------------------------------------------------
// K1 (MFMA): logits = x @ clusters (split bf16: hi*hi + hi*lo + lo*hi),
// BN affine, softmax over 80 cols, write a^T (bf16) + a_sum.
// 256 blocks x 256 thr (4 waves). Block M=128 rows; wave M=32 (two 16-row
// fragment sets), N=80 (5 col-frags), K=512 in 16 steps of 32.
// A-frags: direct global 32B loads (full-line use). B-frags: cpk staged
// through LDS per K-step (shared by 4 waves). Softmax entirely in-wave.
// a^T via LDS bounce -> coalesced 64B global stores.
// ---------------------------------------------------------------------------
__global__ __launch_bounds__(256, 2) void k_assign(
    const float* __restrict__ x, const u16* __restrict__ cpk,
    const float* __restrict__ bn_sc, const float* __restrict__ bn_sh,
    u16* __restrict__ aT, float* __restrict__ asum_g) {
  __shared__ u16 cbuf[5120];        // [h=2][cf=5][lane=64][j=8] one K-step
  __shared__ u16 aTs[64 * 136];     // [col][n_local 0..127] (pad 136)

  int t = threadIdx.x;
  int lane = t & 63;
  int w = t >> 6;
  int l15 = lane & 15, lhi = lane >> 4;
  int r0 = blockIdx.x * 128;
  int b = blockIdx.x >> 3;          // 8 blocks per batch

  f32x4 acc[2][5];
#pragma unroll
  for (int rs = 0; rs < 2; rs++)
#pragma unroll
    for (int cf = 0; cf < 5; cf++) acc[rs][cf] = (f32x4)0.0f;

  const float* xr0 = x + (size_t)(r0 + w * 32 + l15) * 512 + lhi * 8;
  const float* xr1 = xr0 + (size_t)16 * 512;

  for (int kk = 0; kk < 16; kk++) {
    // A loads (independent of LDS)
    f32x4 a00 = *(const f32x4*)(xr0 + kk * 32);
    f32x4 a01 = *(const f32x4*)(xr0 + kk * 32 + 4);
    f32x4 a10 = *(const f32x4*)(xr1 + kk * 32);
    f32x4 a11 = *(const f32x4*)(xr1 + kk * 32 + 4);

    __syncthreads();                // prev step's cbuf reads done
    const u16* src = cpk + (size_t)kk * 5120;
#pragma unroll
    for (int s = 0; s < 3; s++) {
      int c = s * 256 + t;
      if (c < 640) *(short8*)&cbuf[c * 8] = *(const short8*)&src[c * 8];
    }
    __syncthreads();

    short8 ah[2], al[2];
#pragma unroll
    for (int j = 0; j < 4; j++) {
      u16 h, l;
      split2(a00[j], h, l); ah[0][j] = h;     al[0][j] = l;
      split2(a01[j], h, l); ah[0][j + 4] = h; al[0][j + 4] = l;
      split2(a10[j], h, l); ah[1][j] = h;     al[1][j] = l;
      split2(a11[j], h, l); ah[1][j + 4] = h; al[1][j + 4] = l;
    }
#pragma unroll
    for (int cf = 0; cf < 5; cf++) {
      short8 bh = *(const short8*)&cbuf[((0 * 5 + cf) * 64 + lane) * 8];
      short8 bl = *(const short8*)&cbuf[((1 * 5 + cf) * 64 + lane) * 8];
#pragma unroll
      for (int rs = 0; rs < 2; rs++) {
        acc[rs][cf] = __builtin_amdgcn_mfma_f32_16x16x32_bf16(ah[rs], bh, acc[rs][cf], 0, 0, 0);
        acc[rs][cf] = __builtin_amdgcn_mfma_f32_16x16x32_bf16(ah[rs], bl, acc[rs][cf], 0, 0, 0);
        acc[rs][cf] = __builtin_amdgcn_mfma_f32_16x16x32_bf16(al[rs], bh, acc[rs][cf], 0, 0, 0);
      }
    }
  }

  // BN + softmax (in-wave: each 16-lane group holds 4 complete rows)
  float scv[5], shv[5];
#pragma unroll
  for (int cf = 0; cf < 5; cf++) { scv[cf] = bn_sc[cf * 16 + l15]; shv[cf] = bn_sh[cf * 16 + l15]; }

  float psum[4] = {0.f, 0.f, 0.f, 0.f};
#pragma unroll
  for (int rs = 0; rs < 2; rs++) {
#pragma unroll
    for (int reg = 0; reg < 4; reg++) {
      float lv[5], mx = -3.0e38f;
#pragma unroll
      for (int cf = 0; cf < 5; cf++) {
        lv[cf] = fmaf(acc[rs][cf][reg], scv[cf], shv[cf]);
        mx = fmaxf(mx, lv[cf]);
      }
      float M = mx;
      M = fmaxf(M, __shfl_xor(M, 1)); M = fmaxf(M, __shfl_xor(M, 2));
      M = fmaxf(M, __shfl_xor(M, 4)); M = fmaxf(M, __shfl_xor(M, 8));
      float s = 0.f;
#pragma unroll
      for (int cf = 0; cf < 5; cf++) { lv[cf] = __expf(lv[cf] - M); s += lv[cf]; }
      s += __shfl_xor(s, 1); s += __shfl_xor(s, 2);
      s += __shfl_xor(s, 4); s += __shfl_xor(s, 8);
      float inv = 1.0f / s;
      int nl = w * 32 + rs * 16 + lhi * 4 + reg;
#pragma unroll
      for (int cf = 0; cf < 4; cf++) {        // cols 64..79 dropped
        float a = lv[cf] * inv;
        aTs[(cf * 16 + l15) * 136 + nl] = f2bf(a);
        psum[cf] += a;
      }
    }
  }
  // a_sum: add lanes 16/32 apart (same col, other row-groups)
#pragma unroll
  for (int cf = 0; cf < 4; cf++) {
    float p = psum[cf];
    p += __shfl_xor(p, 16); p += __shfl_xor(p, 32);
    if (lane < 16) atomicAdd(&asum_g[b * 64 + cf * 16 + lane], p);
  }
  __syncthreads();
  // a^T write-out: thread t -> col=t>>2, 32 n per seg
  {
    int col = t >> 2, seg = t & 3;
    const u16* sp = &aTs[col * 136 + seg * 32];
    u16* dp = aT + (size_t)col * MT_ + r0 + seg * 32;
#pragma unroll
    for (int i = 0; i < 4; i++) *(short8*)&dp[i * 8] = *(const short8*)&sp[i * 8];
  }
}

// ---------------------------------------------------------------------------
// K2 (MFMA): vlad^T[k][d] = sum_n a^T[k][n]*x[n][d]  - a_sum*c2 (epilogue)
// 512 blocks = (b:32) x (d-tile:16 of 32). bid%8=b%8 -> batch stays on one
// XCD (a^T[b] slice L2-resident). 4 waves: df=w&1 (16 d), nh=w>>1 (n-half).
// A-frags: 16B contiguous loads from a^T. B-frags: 8-dword x-gather
// (64B-coalesced across lanes, every 128B line used once) + rne->bf16.
// n-halves merged via LDS; fused -a_sum*c2, ssq, vlad^T store.
// ---------------------------------------------------------------------------
__global__ __launch_bounds__(256, 2) void k_vlad(
    const float* __restrict__ x, const u16* __restrict__ aT,
    const float* __restrict__ asum_g, const float* __restrict__ c2,
    float* __restrict__ vladT, float* __restrict__ ssq) {
  __shared__ f32x4 mrg[2][4][64];
  __shared__ float wred[4];

  int t = threadIdx.x;
  int lane = t & 63;
  int w = t >> 6;
  int df = w & 1, nh = w >> 1;
  int b = blockIdx.x & 31;
  int d0 = (blockIdx.x >> 5) * 32;
  int l15 = lane & 15, lhi = lane >> 4;
  int dcol = d0 + df * 16 + l15;

  const float* xb = x + (size_t)b * 524288;
  const u16* aTb = aT + (size_t)b * 1024;

  f32x4 vacc[4];
#pragma unroll
  for (int m = 0; m < 4; m++) vacc[m] = (f32x4)0.0f;

#pragma unroll 2
  for (int cc = 0; cc < 16; cc++) {
    int nbase = nh * 512 + cc * 32 + lhi * 8;
    short8 af[4];
#pragma unroll
    for (int m = 0; m < 4; m++)
      af[m] = *(const short8*)&aTb[(size_t)(m * 16 + l15) * MT_ + nbase];
    short8 bx;
#pragma unroll
    for (int j = 0; j < 8; j++)
      bx[j] = (short)f2bf(xb[(size_t)(nbase + j) * 512 + dcol]);
#pragma unroll
    for (int m = 0; m < 4; m++)
      vacc[m] = __builtin_amdgcn_mfma_f32_16x16x32_bf16(af[m], bx, vacc[m], 0, 0, 0);
  }

  if (w >= 2) {
#pragma unroll
    for (int m = 0; m < 4; m++) mrg[df][m][lane] = vacc[m];
  }
  __syncthreads();

  float psq = 0.0f;
  if (w < 2) {
#pragma unroll
    for (int m = 0; m < 4; m++) {
      f32x4 vs = vacc[m] + mrg[df][m][lane];
      f32x4 av = *(const f32x4*)&asum_g[b * 64 + m * 16 + lhi * 4];
      f32x4 cv = *(const f32x4*)&c2[(size_t)dcol * 64 + m * 16 + lhi * 4];
#pragma unroll
      for (int r = 0; r < 4; r++) {
        float val = vs[r] - av[r] * cv[r];
        psq += val * val;
        vladT[(size_t)b * 32768 + (size_t)(m * 16 + lhi * 4 + r) * 512 + dcol] = val;
      }
    }
  }
  psq += __shfl_xor(psq, 1);  psq += __shfl_xor(psq, 2);
  psq += __shfl_xor(psq, 4);  psq += __shfl_xor(psq, 8);
  psq += __shfl_xor(psq, 16); psq += __shfl_xor(psq, 32);
  if ((t & 63) == 0) wred[w] = psq;
  __syncthreads();
  if (t == 0) atomicAdd(&ssq[b], wred[0] + wred[1] + wred[2] + wred[3]);
}

// ---------------------------------------------------------------------------
// K3: fold both L2 norms into one per-batch scale.
// ---------------------------------------------------------------------------
__global__ void k_scale(const float* __restrict__ ssq, float* __restrict__ scale) {
  int t = threadIdx.x;
  if (t < B_) {
    float S = ssq[t];
    float n1 = sqrtf(S + 1e-12f);
    float n2 = sqrtf(S / (S + 1e-12f) + 1e-12f);
    scale[t] = 1.0f / (n1 * n2);
  }
}

// ---------------------------------------------------------------------------
// K4: out[b][d*64+k] = vlad^T[b][k][d] * scale[b]   (LDS tile transpose)
// grid 256 = (b:32) x (d-tile:8 of 64)
// ---------------------------------------------------------------------------
__global__ __launch_bounds__(256) void k_out(const float* __restrict__ vladT,
                                             const float* __restrict__ scale,
                                             float* __restrict__ out) {
  __shared__ float ts[64 * 68];
  int t = threadIdx.x;
  int b = blockIdx.x >> 3;
  int d0 = (blockIdx.x & 7) * 64;

  int kr = t >> 4, cs = (t & 15) * 4;
#pragma unroll
  for (int i = 0; i < 4; i++) {
    int k = kr + i * 16;
    f32x4 v = *(const f32x4*)&vladT[(size_t)b * 32768 + (size_t)k * 512 + d0 + cs];
    *(f32x4*)&ts[k * 68 + cs] = v;
  }
  __syncthreads();
  float s = scale[b];
  int dloc = t >> 2, ks = (t & 3) * 16;
  float* op = out + (size_t)b * 32768 + (size_t)(d0 + dloc) * 64 + ks;
#pragma unroll
  for (int q = 0; q < 4; q++) {
    f32x4 o;
#pragma unroll
    for (int r = 0; r < 4; r++) o[r] = ts[(ks + q * 4 + r) * 68 + dloc] * s;
    *(f32x4*)&op[q * 4] = o;
  }
}

extern "C" void kernel_launch(void* const* d_in, const int* in_sizes, int n_in,
                              void* d_out, int out_size, void* d_ws, size_t ws_size,
                              hipStream_t stream) {
  const float* x        = (const float*)d_in[0];
  const float* clusters = (const float*)d_in[1];
  const float* clusters2= (const float*)d_in[2];
  const float* bn_w     = (const float*)d_in[3];
  const float* bn_b     = (const float*)d_in[4];
  const float* bn_m     = (const float*)d_in[5];
  const float* bn_v     = (const float*)d_in[6];
  float* out = (float*)d_out;

  char* ws = (char*)d_ws;
  u16*   aT    = (u16*)ws;                             // 64*32768 bf16 = 4 MB
  float* vladT = (float*)(ws + (size_t)4 * 1048576);   // 32*64*512 f32 = 4 MB
  u16*   cpk   = (u16*)(ws + (size_t)8 * 1048576);     // 163840 B
  float* bn_sc = (float*)(ws + (size_t)8 * 1048576 + 200704);
  float* bn_sh = bn_sc + KG_;
  float* asum  = bn_sh + KG_;                          // 2048 f32
  float* ssq   = asum + B_ * K_;                       // 32 f32
  float* scale = ssq + B_;                             // 32 f32

  k_prep<<<20, 256, 0, stream>>>(clusters, bn_w, bn_b, bn_m, bn_v,
                                 cpk, bn_sc, bn_sh, asum, ssq);
  k_assign<<<256, 256, 0, stream>>>(x, cpk, bn_sc, bn_sh, aT, asum);
  k_vlad<<<512, 256, 0, stream>>>(x, aT, asum, clusters2, vladT, ssq);
  k_scale<<<1, 64, 0, stream>>>(ssq, scale);
  k_out<<<256, 256, 0, stream>>>(vladT, scale, out);
}

// Round 6
// 149.796 us; speedup vs baseline: 1.4402x; 1.0380x over previous
//
#include <hip/hip_runtime.h>

typedef unsigned short u16;
typedef float f32x4 __attribute__((ext_vector_type(4)));
typedef short short8 __attribute__((ext_vector_type(8)));

#define B_ 32
#define N_ 1024
#define D_ 512
#define K_ 64
#define KG_ 80
#define MT_ 32768          // total rows B*N

__device__ __forceinline__ u16 f2bf(float f) {
  union { float f; unsigned u; } x; x.f = f;
  unsigned u = x.u;
  u += 0x7FFFu + ((u >> 16) & 1u);          // RNE, finite data
  return (u16)(u >> 16);
}
__device__ __forceinline__ void split2(float v, u16& h, u16& l) {
  union { float f; unsigned u; } x; x.f = v;
  unsigned hu = x.u & 0xFFFF0000u;          // truncate -> hi
  h = (u16)(hu >> 16);
  union { unsigned u; float f; } hf; hf.u = hu;
  l = f2bf(v - hf.f);                       // exact remainder, rne -> lo
}

// ---------------------------------------------------------------------------
// K0: BN fold; zero accumulators; pack clusters into MFMA B-fragments
// (hi/lo split).  cpk layout: [kk=16][h=2][cf=5][lane=64][j=8] u16
//   element = clusters[d=kk*32+(lane>>4)*8+j][col=cf*16+(lane&15)]
// ---------------------------------------------------------------------------
__global__ void k_prep(const float* __restrict__ clusters,
                       const float* __restrict__ bn_w, const float* __restrict__ bn_b,
                       const float* __restrict__ bn_m, const float* __restrict__ bn_v,
                       u16* __restrict__ cpk, float* __restrict__ bn_sc,
                       float* __restrict__ bn_sh,
                       float* __restrict__ asum, float* __restrict__ ssq) {
  int t = blockIdx.x * 256 + threadIdx.x;
  if (t < KG_) {
    float sc = bn_w[t] * rsqrtf(bn_v[t] + 1e-5f);
    bn_sc[t] = sc;
    bn_sh[t] = bn_b[t] - bn_m[t] * sc;
  }
  if (t < B_ * K_) asum[t] = 0.0f;
  if (t < B_) ssq[t] = 0.0f;
  if (t < 5120) {                            // (kk*5+cf)*64 + lane
    int grp = t >> 6;
    int kk = grp / 5, cf = grp % 5;
    int lane = t & 63;
    int col = cf * 16 + (lane & 15);
#pragma unroll
    for (int j = 0; j < 8; j++) {
      int d = kk * 32 + ((lane >> 4) << 3) + j;
      float v = clusters[(size_t)d * 80 + col];
      u16 h, l; split2(v, h, l);
      cpk[(size_t)kk * 5120 + ((0 * 5 + cf) * 64 + lane) * 8 + j] = h;
      cpk[(size_t)kk * 5120 + ((1 * 5 + cf) * 64 + lane) * 8 + j] = l;
    }
  }
}

// ---------------------------------------------------------------------------
// K1 (MFMA): logits = x @ clusters (split bf16: hh + hl + lh), BN, softmax
// over 80, write a^T bf16 + a_sum.  256 blocks x 256 thr (4 waves), M=128.
// Double-buffered cbuf (ONE barrier/K-step) + depth-1 prefetch of A-frags
// and staging regs -> x streams at HBM rate despite 1 block/CU.
// ---------------------------------------------------------------------------
__global__ __launch_bounds__(256, 2) void k_assign(
    const float* __restrict__ x, const u16* __restrict__ cpk,
    const float* __restrict__ bn_sc, const float* __restrict__ bn_sh,
    u16* __restrict__ aT, float* __restrict__ asum_g) {
  __shared__ u16 cbuf[2][5120];     // [h=2][cf=5][lane=64][j=8] per buffer
  __shared__ u16 aTs[64 * 136];     // [col][n_local 0..127] (pad 136)

  int t = threadIdx.x;
  int lane = t & 63;
  int w = t >> 6;
  int l15 = lane & 15, lhi = lane >> 4;
  int r0 = blockIdx.x * 128;
  int b = blockIdx.x >> 3;          // 8 blocks per batch

  f32x4 acc[2][5];
#pragma unroll
  for (int rs = 0; rs < 2; rs++)
#pragma unroll
    for (int cf = 0; cf < 5; cf++) acc[rs][cf] = (f32x4)0.0f;

  const float* xr0 = x + (size_t)(r0 + w * 32 + l15) * 512 + lhi * 8;
  const float* xr1 = xr0 + (size_t)16 * 512;

  f32x4 aA[4], aB[4];
  short8 sg[3];

#define STAGE_LD(kk) { const short8* sp = (const short8*)(cpk + (size_t)(kk) * 5120); \
    sg[0] = sp[t]; sg[1] = sp[t + 256]; if (t < 128) sg[2] = sp[t + 512]; }
#define STAGE_ST(bufi) { short8* dp = (short8*)cbuf[bufi]; \
    dp[t] = sg[0]; dp[t + 256] = sg[1]; if (t < 128) dp[t + 512] = sg[2]; }
#define LOADA(ar, kk) { ar[0] = *(const f32x4*)(xr0 + (kk) * 32); \
    ar[1] = *(const f32x4*)(xr0 + (kk) * 32 + 4); \
    ar[2] = *(const f32x4*)(xr1 + (kk) * 32); \
    ar[3] = *(const f32x4*)(xr1 + (kk) * 32 + 4); }
#define COMPUTE(ar, cur) { \
    short8 ah[2], al[2]; u16 h_, l_; \
    _Pragma("unroll") \
    for (int j = 0; j < 4; j++) { \
      split2(ar[0][j], h_, l_); ah[0][j] = h_;     al[0][j] = l_; \
      split2(ar[1][j], h_, l_); ah[0][j + 4] = h_; al[0][j + 4] = l_; \
      split2(ar[2][j], h_, l_); ah[1][j] = h_;     al[1][j] = l_; \
      split2(ar[3][j], h_, l_); ah[1][j + 4] = h_; al[1][j + 4] = l_; \
    } \
    _Pragma("unroll") \
    for (int cf = 0; cf < 5; cf++) { \
      short8 bh = *(const short8*)&cbuf[cur][((0 * 5 + cf) * 64 + lane) * 8]; \
      short8 bl = *(const short8*)&cbuf[cur][((1 * 5 + cf) * 64 + lane) * 8]; \
      _Pragma("unroll") \
      for (int rs = 0; rs < 2; rs++) { \
        acc[rs][cf] = __builtin_amdgcn_mfma_f32_16x16x32_bf16(ah[rs], bh, acc[rs][cf], 0, 0, 0); \
        acc[rs][cf] = __builtin_amdgcn_mfma_f32_16x16x32_bf16(ah[rs], bl, acc[rs][cf], 0, 0, 0); \
        acc[rs][cf] = __builtin_amdgcn_mfma_f32_16x16x32_bf16(al[rs], bh, acc[rs][cf], 0, 0, 0); \
      } \
    } }

  STAGE_LD(0); STAGE_ST(0); LOADA(aA, 0);
  __syncthreads();
#pragma unroll
  for (int kk = 0; kk < 16; kk += 2) {
    if (kk + 1 < 16) { STAGE_LD(kk + 1); LOADA(aB, kk + 1); }
    COMPUTE(aA, 0);
    if (kk + 1 < 16) STAGE_ST(1);
    __syncthreads();
    if (kk + 2 < 16) { STAGE_LD(kk + 2); LOADA(aA, kk + 2); }
    if (kk + 1 < 16) COMPUTE(aB, 1);
    if (kk + 2 < 16) STAGE_ST(0);
    __syncthreads();
  }

  // BN + softmax (in-wave: each 16-lane group holds complete rows)
  float scv[5], shv[5];
#pragma unroll
  for (int cf = 0; cf < 5; cf++) { scv[cf] = bn_sc[cf * 16 + l15]; shv[cf] = bn_sh[cf * 16 + l15]; }

  float psum[4] = {0.f, 0.f, 0.f, 0.f};
#pragma unroll
  for (int rs = 0; rs < 2; rs++) {
#pragma unroll
    for (int reg = 0; reg < 4; reg++) {
      float lv[5], mx = -3.0e38f;
#pragma unroll
      for (int cf = 0; cf < 5; cf++) {
        lv[cf] = fmaf(acc[rs][cf][reg], scv[cf], shv[cf]);
        mx = fmaxf(mx, lv[cf]);
      }
      float M = mx;
      M = fmaxf(M, __shfl_xor(M, 1)); M = fmaxf(M, __shfl_xor(M, 2));
      M = fmaxf(M, __shfl_xor(M, 4)); M = fmaxf(M, __shfl_xor(M, 8));
      float s = 0.f;
#pragma unroll
      for (int cf = 0; cf < 5; cf++) { lv[cf] = __expf(lv[cf] - M); s += lv[cf]; }
      s += __shfl_xor(s, 1); s += __shfl_xor(s, 2);
      s += __shfl_xor(s, 4); s += __shfl_xor(s, 8);
      float inv = 1.0f / s;
      int nl = w * 32 + rs * 16 + lhi * 4 + reg;
#pragma unroll
      for (int cf = 0; cf < 4; cf++) {        // cols 64..79 dropped
        float a = lv[cf] * inv;
        aTs[(cf * 16 + l15) * 136 + nl] = f2bf(a);
        psum[cf] += a;
      }
    }
  }
#pragma unroll
  for (int cf = 0; cf < 4; cf++) {
    float p = psum[cf];
    p += __shfl_xor(p, 16); p += __shfl_xor(p, 32);
    if (lane < 16) atomicAdd(&asum_g[b * 64 + cf * 16 + lane], p);
  }
  __syncthreads();
  {
    int col = t >> 2, seg = t & 3;
    const u16* sp = &aTs[col * 136 + seg * 32];
    u16* dp = aT + (size_t)col * MT_ + r0 + seg * 32;
#pragma unroll
    for (int i = 0; i < 4; i++) *(short8*)&dp[i * 8] = *(const short8*)&sp[i * 8];
  }
}

// ---------------------------------------------------------------------------
// K2 (MFMA): vlad^T[k][d] = sum_n a^T[k][n]*x[n][d] - a_sum*c2 (epilogue).
// 1024 blocks = 32 b x 32 d-tiles(16) -> 4 blocks/CU, 16 waves/CU.
// Bijective XCD map: all 32 d-tiles of batch b on XCD b&7 (x[b]=2MB in L2,
// adjacent tiles share 128B lines). Wave w = n-quarter; depth-1 prefetch;
// 4-way merge via LDS; wave w does epilogue for k-frag w.
// ---------------------------------------------------------------------------
__global__ __launch_bounds__(256, 4) void k_vlad(
    const float* __restrict__ x, const u16* __restrict__ aT,
    const float* __restrict__ asum_g, const float* __restrict__ c2,
    float* __restrict__ vladT, float* __restrict__ ssq) {
  __shared__ f32x4 mrg[4][4][64];   // [wave][m][lane]
  __shared__ float wred[4];

  int t = threadIdx.x;
  int lane = t & 63;
  int w = t >> 6;
  int i = blockIdx.x;
  int b = (i & 7) | (((i >> 8) & 3) << 3);
  int dt = (i >> 3) & 31;
  int d0 = dt * 16;
  int l15 = lane & 15, lhi = lane >> 4;
  int dcol = d0 + l15;

  const float* xb = x + (size_t)b * 524288;
  const u16* aTb = aT + (size_t)b * 1024;

  f32x4 vacc[4];
#pragma unroll
  for (int m = 0; m < 4; m++) vacc[m] = (f32x4)0.0f;

  short8 afA[4], afB[4];
  float xpA[8], xpB[8];

#define VLOAD(af, xp, cc) { int nb = w * 256 + (cc) * 32 + lhi * 8; \
    _Pragma("unroll") \
    for (int m = 0; m < 4; m++) \
      af[m] = *(const short8*)&aTb[(size_t)(m * 16 + l15) * MT_ + nb]; \
    _Pragma("unroll") \
    for (int j = 0; j < 8; j++) xp[j] = xb[(size_t)(nb + j) * 512 + dcol]; }
#define VMFMA(af, xp) { short8 bx; \
    _Pragma("unroll") \
    for (int j = 0; j < 8; j++) bx[j] = (short)f2bf(xp[j]); \
    _Pragma("unroll") \
    for (int m = 0; m < 4; m++) \
      vacc[m] = __builtin_amdgcn_mfma_f32_16x16x32_bf16(af[m], bx, vacc[m], 0, 0, 0); }

  VLOAD(afA, xpA, 0);
#pragma unroll
  for (int cc = 0; cc < 8; cc += 2) {
    if (cc + 1 < 8) VLOAD(afB, xpB, cc + 1);
    VMFMA(afA, xpA);
    if (cc + 2 < 8) VLOAD(afA, xpA, cc + 2);
    if (cc + 1 < 8) VMFMA(afB, xpB);
  }

#pragma unroll
  for (int m = 0; m < 4; m++) mrg[w][m][lane] = vacc[m];
  __syncthreads();

  // wave w handles k-frag m=w
  f32x4 vs = mrg[0][w][lane] + mrg[1][w][lane] + mrg[2][w][lane] + mrg[3][w][lane];
  f32x4 av = *(const f32x4*)&asum_g[b * 64 + w * 16 + lhi * 4];
  f32x4 cv = *(const f32x4*)&c2[(size_t)dcol * 64 + w * 16 + lhi * 4];
  float psq = 0.0f;
#pragma unroll
  for (int r = 0; r < 4; r++) {
    float val = vs[r] - av[r] * cv[r];
    psq += val * val;
    vladT[(size_t)b * 32768 + (size_t)(w * 16 + lhi * 4 + r) * 512 + dcol] = val;
  }
  psq += __shfl_xor(psq, 1);  psq += __shfl_xor(psq, 2);
  psq += __shfl_xor(psq, 4);  psq += __shfl_xor(psq, 8);
  psq += __shfl_xor(psq, 16); psq += __shfl_xor(psq, 32);
  if (lane == 0) wred[w] = psq;
  __syncthreads();
  if (t == 0) atomicAdd(&ssq[b], wred[0] + wred[1] + wred[2] + wred[3]);
}

// ---------------------------------------------------------------------------
// K3: out[b][d*64+k] = vlad^T[b][k][d] / (n1*n2)  (LDS tile transpose;
// per-batch scale computed in-block from ssq -> k_scale launch removed)
// grid 256 = (b:32) x (d-tile:8 of 64)
// ---------------------------------------------------------------------------
__global__ __launch_bounds__(256) void k_out(const float* __restrict__ vladT,
                                             const float* __restrict__ ssq,
                                             float* __restrict__ out) {
  __shared__ float ts[64 * 68];
  int t = threadIdx.x;
  int b = blockIdx.x >> 3;
  int d0 = (blockIdx.x & 7) * 64;

  float S = ssq[b];
  float n1 = sqrtf(S + 1e-12f);
  float n2 = sqrtf(S / (S + 1e-12f) + 1e-12f);
  float s = 1.0f / (n1 * n2);

  int kr = t >> 4, cs = (t & 15) * 4;
#pragma unroll
  for (int i = 0; i < 4; i++) {
    int k = kr + i * 16;
    f32x4 v = *(const f32x4*)&vladT[(size_t)b * 32768 + (size_t)k * 512 + d0 + cs];
    *(f32x4*)&ts[k * 68 + cs] = v;
  }
  __syncthreads();
  int dloc = t >> 2, ks = (t & 3) * 16;
  float* op = out + (size_t)b * 32768 + (size_t)(d0 + dloc) * 64 + ks;
#pragma unroll
  for (int q = 0; q < 4; q++) {
    f32x4 o;
#pragma unroll
    for (int r = 0; r < 4; r++) o[r] = ts[(ks + q * 4 + r) * 68 + dloc] * s;
    *(f32x4*)&op[q * 4] = o;
  }
}

extern "C" void kernel_launch(void* const* d_in, const int* in_sizes, int n_in,
                              void* d_out, int out_size, void* d_ws, size_t ws_size,
                              hipStream_t stream) {
  const float* x        = (const float*)d_in[0];
  const float* clusters = (const float*)d_in[1];
  const float* clusters2= (const float*)d_in[2];
  const float* bn_w     = (const float*)d_in[3];
  const float* bn_b     = (const float*)d_in[4];
  const float* bn_m     = (const float*)d_in[5];
  const float* bn_v     = (const float*)d_in[6];
  float* out = (float*)d_out;

  char* ws = (char*)d_ws;
  u16*   aT    = (u16*)ws;                             // 64*32768 bf16 = 4 MB
  float* vladT = (float*)(ws + (size_t)4 * 1048576);   // 32*64*512 f32 = 4 MB
  u16*   cpk   = (u16*)(ws + (size_t)8 * 1048576);     // 163840 B
  float* bn_sc = (float*)(ws + (size_t)8 * 1048576 + 200704);
  float* bn_sh = bn_sc + KG_;
  float* asum  = bn_sh + KG_;                          // 2048 f32
  float* ssq   = asum + B_ * K_;                       // 32 f32

  k_prep<<<20, 256, 0, stream>>>(clusters, bn_w, bn_b, bn_m, bn_v,
                                 cpk, bn_sc, bn_sh, asum, ssq);
  k_assign<<<256, 256, 0, stream>>>(x, cpk, bn_sc, bn_sh, aT, asum);
  k_vlad<<<1024, 256, 0, stream>>>(x, aT, asum, clusters2, vladT, ssq);
  k_out<<<256, 256, 0, stream>>>(vladT, ssq, out);
}